// Round 5
// baseline (102.544 us; speedup 1.0000x reference)
//
#include <hip/hip_runtime.h>
#include <math.h>

// Chamfer distance, N=M=16384, D=3, fp32.
// R7: back to TWO-PASS, pk-packed. R6's fused kernel spent its win on
// overhead (VALU busy 57.5k cy/SIMD ~= R4's 59.6k despite forced pk-asm):
// CM subreg mins + seed pk_add + flush chains + 4 barriers/block at 2.6
// waves/SIMD. Two-pass is 3 pk_fma + 1 min3 per 2 pairs per pass (4.0
// VALU/pair total vs fused's ~3.8 + machinery) with ZERO cross-thread
// reduction: row-min lives in registers, sa hoisted out of the loop
// (re-added in sum kernel), one barrier per block, 16KB LDS, no cms.
// Model: 2*2.68e8 pairs * 2.0/64 lanes * 2cy / 1024 SIMD ~= 14us VALU floor.

typedef float v2f __attribute__((ext_vector_type(2)));
typedef float v4f __attribute__((ext_vector_type(4)));

constexpr int N       = 16384;
constexpr int THREADS = 256;
constexpr int K       = 4;                    // i's per thread (registers)
constexpr int IBLK    = N / (THREADS * K);    // 16 i-blocks
constexpr float INF_F = 3.402823466e+38f;

static __device__ __forceinline__ v2f pk_fma(v2f a, v2f b, v2f c) {
  v2f d;
  asm("v_pk_fma_f32 %0, %1, %2, %3" : "=v"(d) : "v"(a), "v"(b), "v"(c));
  return d;
}

// Block (pass, jck, ig): i-tile = ig*1024 + [0,1024) of src, j-chunk
// [jck*jrange, +jrange) of oth. Tracks min_j(|b|^2 - 2 a.b); |a|^2 is
// re-added in chamfer_sum (min commutes with +const).
__global__ __launch_bounds__(THREADS, 4) void chamfer_pass(
    const float* __restrict__ p1, const float* __restrict__ p2,
    float* __restrict__ partial, float* __restrict__ out,
    int jrange, int JC) {
  __shared__ __align__(16) float bls[4 * 1024];  // -2x | -2y | -2z | |b|^2

  const int tid = threadIdx.x;
  const int bid = blockIdx.x;
  const int per = IBLK * JC;
  const int pass = (bid >= per) ? 1 : 0;
  const int rem = bid - pass * per;
  const int jck = rem >> 4;          // / IBLK (=16)
  const int ig  = rem & (IBLK - 1);
  const float* __restrict__ src = pass ? p2 : p1;  // "i" side
  const float* __restrict__ oth = pass ? p1 : p2;  // "j" side

  if (bid == 0 && tid == 0) *out = 0.0f;  // ordered before sum's atomics

  const int j0 = jck * jrange;
  for (int t = tid; t < jrange; t += THREADS) {
    const float* bp = oth + (size_t)(j0 + t) * 3;
    const float x = bp[0], y = bp[1], z = bp[2];
    bls[t]        = -2.0f * x;
    bls[1024 + t] = -2.0f * y;
    bls[2048 + t] = -2.0f * z;
    bls[3072 + t] = fmaf(x, x, fmaf(y, y, z * z));
  }

  // K=4 i-points per thread, coords duplicated into v2f once (reused over
  // all j's). i = i0 + q*THREADS -> coalesced loads and stores.
  const int i0 = ig * (THREADS * K) + tid;
#define LOADI(q)                                                   \
  v2f AX##q, AY##q, AZ##q;                                         \
  {                                                                \
    const float* ap = src + (size_t)(i0 + (q)*THREADS) * 3;        \
    const float x = ap[0], y = ap[1], z = ap[2];                   \
    AX##q = {x, x}; AY##q = {y, y}; AZ##q = {z, z};                \
  }
  LOADI(0) LOADI(1) LOADI(2) LOADI(3)
#undef LOADI
  float RM0 = INF_F, RM1 = INF_F, RM2 = INF_F, RM3 = INF_F;

  __syncthreads();

  // Inner loop: 4 j's per iter. 4 uniform (broadcast) ds_read_b128 +
  // 8 independent 3-deep pk_fma chains + 8 min3. 2.0 VALU / pair.
#pragma unroll 2
  for (int j = 0; j < jrange; j += 4) {
    const v4f X = *(const v4f*)&bls[j];
    const v4f Y = *(const v4f*)&bls[1024 + j];
    const v4f Z = *(const v4f*)&bls[2048 + j];
    const v4f W = *(const v4f*)&bls[3072 + j];
    const v2f X01 = {X.x, X.y}, X23 = {X.z, X.w};
    const v2f Y01 = {Y.x, Y.y}, Y23 = {Y.z, Y.w};
    const v2f Z01 = {Z.x, Z.y}, Z23 = {Z.z, Z.w};
    const v2f W01 = {W.x, W.y}, W23 = {W.z, W.w};
#define ROWQ(q)                                                             \
  {                                                                         \
    const v2f d0 =                                                          \
        pk_fma(AX##q, X01, pk_fma(AY##q, Y01, pk_fma(AZ##q, Z01, W01)));    \
    RM##q = fminf(fminf(RM##q, d0.x), d0.y);                                \
    const v2f d1 =                                                          \
        pk_fma(AX##q, X23, pk_fma(AY##q, Y23, pk_fma(AZ##q, Z23, W23)));    \
    RM##q = fminf(fminf(RM##q, d1.x), d1.y);                                \
  }
    ROWQ(0) ROWQ(1) ROWQ(2) ROWQ(3)
#undef ROWQ
  }

  float* dst = partial + (size_t)(pass * JC + jck) * N;
  dst[i0 + 0 * THREADS] = RM0;
  dst[i0 + 1 * THREADS] = RM1;
  dst[i0 + 2 * THREADS] = RM2;
  dst[i0 + 3 * THREADS] = RM3;
}

// One thread per point (2*16384): min over JC chunk-partials (4 independent
// accumulators so loads pipeline), re-add |a|^2, sqrt, block-sum, one
// atomicAdd per block into out[0].
__global__ __launch_bounds__(THREADS) void chamfer_sum(
    const float* __restrict__ p1, const float* __restrict__ p2,
    const float* __restrict__ partial, float* __restrict__ out, int JC) {
  const int p = blockIdx.x * THREADS + threadIdx.x;  // 0..32767
  const int pass = p >> 14;
  const int i = p & (N - 1);
  const float* __restrict__ pts = pass ? p2 : p1;

  const float x = pts[i * 3 + 0], y = pts[i * 3 + 1], z = pts[i * 3 + 2];
  const float sa = fmaf(x, x, fmaf(y, y, z * z));

  const float* bp = partial + (size_t)pass * JC * N + i;
  float m0 = INF_F, m1 = INF_F, m2 = INF_F, m3 = INF_F;
  for (int c = 0; c < JC; c += 4) {
    m0 = fminf(m0, bp[(size_t)(c + 0) * N]);
    m1 = fminf(m1, bp[(size_t)(c + 1) * N]);
    m2 = fminf(m2, bp[(size_t)(c + 2) * N]);
    m3 = fminf(m3, bp[(size_t)(c + 3) * N]);
  }
  const float m = fminf(fminf(m0, m1), fminf(m2, m3));
  float d = sqrtf(fmaxf(sa + m, 0.0f));

  for (int off = 32; off > 0; off >>= 1) d += __shfl_down(d, off, 64);
  __shared__ float red[THREADS / 64];
  const int wave = threadIdx.x >> 6;
  const int lane = threadIdx.x & 63;
  if (lane == 0) red[wave] = d;
  __syncthreads();
  if (threadIdx.x == 0) {
    float s = 0.0f;
    for (int w = 0; w < THREADS / 64; ++w) s += red[w];
    atomicAdd(out, s);
  }
}

extern "C" void kernel_launch(void* const* d_in, const int* in_sizes, int n_in,
                              void* d_out, int out_size, void* d_ws, size_t ws_size,
                              hipStream_t stream) {
  const float* p1 = (const float*)d_in[0];
  const float* p2 = (const float*)d_in[1];
  float* out = (float*)d_out;
  float* partial = (float*)d_ws;

  // ws: partial[2][JC][N]. JC=64 -> 8 MB (R4/R6 proved available); degrade
  // if tight. jrange = N/JC <= 1024 fits the 16KB bls staging buffer.
  const size_t F = ws_size / sizeof(float);
  int JC = 64;
  while (JC > 16 && (size_t)(2 * JC) * N > F) JC >>= 1;
  const int jrange = N / JC;

  const int grid = 2 * IBLK * JC;            // 2048 @ JC=64
  chamfer_pass<<<dim3(grid), THREADS, 0, stream>>>(p1, p2, partial, out,
                                                   jrange, JC);
  chamfer_sum<<<dim3((2 * N) / THREADS), THREADS, 0, stream>>>(p1, p2, partial,
                                                               out, JC);
}

// Round 6
// 102.265 us; speedup vs baseline: 1.0027x; 1.0027x over previous
//
#include <hip/hip_runtime.h>
#include <math.h>

// Chamfer distance, N=M=16384, D=3, fp32.
// R8 = R7 with K: 4 -> 8 i's/thread and guaranteed v_min3_f32.
// R7 post-mortem: 69k busy cy/SIMD (2.1x model) at 63% VALUBusy; LDS
// broadcast ds_read_b128 was a co-bottleneck (27us of LDS pipe for the
// whole kernel, 48:134 LDS:VALU cycles per body, serialized via lgkmcnt).
// K=8 halves LDS traffic per pair (32 pairs per ds_read), halves loop
// overhead per pair, and shrinks LDS to 4KB. min3 forced via inline asm.
// Body: 4 ds_read + 48 pk_fma + 16 min3 = 2.0 VALU/pair, LDS:VALU 32:128.

typedef float v2f __attribute__((ext_vector_type(2)));
typedef float v4f __attribute__((ext_vector_type(4)));

constexpr int N       = 16384;
constexpr int THREADS = 256;
constexpr int K       = 8;                    // i's per thread (registers)
constexpr int IBLK    = N / (THREADS * K);    // 8 i-blocks
constexpr float INF_F = 3.402823466e+38f;

static __device__ __forceinline__ v2f pk_fma(v2f a, v2f b, v2f c) {
  v2f d;
  asm("v_pk_fma_f32 %0, %1, %2, %3" : "=v"(d) : "v"(a), "v"(b), "v"(c));
  return d;
}
static __device__ __forceinline__ float min3f(float a, float b, float c) {
  float d;
  asm("v_min3_f32 %0, %1, %2, %3" : "=v"(d) : "v"(a), "v"(b), "v"(c));
  return d;
}

// Block (pass, jck, ig): i-tile = ig*2048 + [0,2048) of src, j-chunk
// [jck*jrange, +jrange) of oth. Tracks min_j(|b|^2 - 2 a.b); |a|^2 is
// re-added in chamfer_sum (min commutes with +const).
__global__ __launch_bounds__(THREADS, 4) void chamfer_pass(
    const float* __restrict__ p1, const float* __restrict__ p2,
    float* __restrict__ partial, float* __restrict__ out,
    int jrange, int JC) {
  __shared__ __align__(16) float bls[4 * 1024];  // -2x | -2y | -2z | |b|^2

  const int tid = threadIdx.x;
  const int bid = blockIdx.x;
  const int per = IBLK * JC;
  const int pass = (bid >= per) ? 1 : 0;
  const int rem = bid - pass * per;
  const int jck = rem >> 3;          // / IBLK (=8)
  const int ig  = rem & (IBLK - 1);
  const float* __restrict__ src = pass ? p2 : p1;  // "i" side
  const float* __restrict__ oth = pass ? p1 : p2;  // "j" side

  if (bid == 0 && tid == 0) *out = 0.0f;  // ordered before sum's atomics

  const int j0 = jck * jrange;
  for (int t = tid; t < jrange; t += THREADS) {
    const float* bp = oth + (size_t)(j0 + t) * 3;
    const float x = bp[0], y = bp[1], z = bp[2];
    bls[t]        = -2.0f * x;
    bls[1024 + t] = -2.0f * y;
    bls[2048 + t] = -2.0f * z;
    bls[3072 + t] = fmaf(x, x, fmaf(y, y, z * z));
  }

  // K=8 i-points per thread, coords duplicated into v2f once (reused over
  // all j's). i = i0 + q*THREADS -> coalesced loads and stores.
  const int i0 = ig * (THREADS * K) + tid;
#define LOADI(q)                                                   \
  v2f AX##q, AY##q, AZ##q;                                         \
  {                                                                \
    const float* ap = src + (size_t)(i0 + (q)*THREADS) * 3;        \
    const float x = ap[0], y = ap[1], z = ap[2];                   \
    AX##q = {x, x}; AY##q = {y, y}; AZ##q = {z, z};                \
  }
  LOADI(0) LOADI(1) LOADI(2) LOADI(3)
  LOADI(4) LOADI(5) LOADI(6) LOADI(7)
#undef LOADI
  float RM0 = INF_F, RM1 = INF_F, RM2 = INF_F, RM3 = INF_F;
  float RM4 = INF_F, RM5 = INF_F, RM6 = INF_F, RM7 = INF_F;

  __syncthreads();

  // Inner loop: 4 j's x 8 i's per iter. 4 uniform (broadcast) ds_read_b128
  // + 8 independent pairs of 3-deep pk_fma chains + 16 min3.
#pragma unroll 2
  for (int j = 0; j < jrange; j += 4) {
    const v4f X = *(const v4f*)&bls[j];
    const v4f Y = *(const v4f*)&bls[1024 + j];
    const v4f Z = *(const v4f*)&bls[2048 + j];
    const v4f W = *(const v4f*)&bls[3072 + j];
    const v2f X01 = {X.x, X.y}, X23 = {X.z, X.w};
    const v2f Y01 = {Y.x, Y.y}, Y23 = {Y.z, Y.w};
    const v2f Z01 = {Z.x, Z.y}, Z23 = {Z.z, Z.w};
    const v2f W01 = {W.x, W.y}, W23 = {W.z, W.w};
#define ROWQ(q)                                                             \
  {                                                                         \
    const v2f d0 =                                                          \
        pk_fma(AX##q, X01, pk_fma(AY##q, Y01, pk_fma(AZ##q, Z01, W01)));    \
    const v2f d1 =                                                          \
        pk_fma(AX##q, X23, pk_fma(AY##q, Y23, pk_fma(AZ##q, Z23, W23)));    \
    RM##q = min3f(RM##q, d0.x, d0.y);                                       \
    RM##q = min3f(RM##q, d1.x, d1.y);                                       \
  }
    ROWQ(0) ROWQ(1) ROWQ(2) ROWQ(3)
    ROWQ(4) ROWQ(5) ROWQ(6) ROWQ(7)
#undef ROWQ
  }

  float* dst = partial + (size_t)(pass * JC + jck) * N;
  dst[i0 + 0 * THREADS] = RM0;
  dst[i0 + 1 * THREADS] = RM1;
  dst[i0 + 2 * THREADS] = RM2;
  dst[i0 + 3 * THREADS] = RM3;
  dst[i0 + 4 * THREADS] = RM4;
  dst[i0 + 5 * THREADS] = RM5;
  dst[i0 + 6 * THREADS] = RM6;
  dst[i0 + 7 * THREADS] = RM7;
}

// One thread per point (2*16384): min over JC chunk-partials (4 independent
// accumulators so loads pipeline), re-add |a|^2, sqrt, block-sum, one
// atomicAdd per block into out[0].
__global__ __launch_bounds__(THREADS) void chamfer_sum(
    const float* __restrict__ p1, const float* __restrict__ p2,
    const float* __restrict__ partial, float* __restrict__ out, int JC) {
  const int p = blockIdx.x * THREADS + threadIdx.x;  // 0..32767
  const int pass = p >> 14;
  const int i = p & (N - 1);
  const float* __restrict__ pts = pass ? p2 : p1;

  const float x = pts[i * 3 + 0], y = pts[i * 3 + 1], z = pts[i * 3 + 2];
  const float sa = fmaf(x, x, fmaf(y, y, z * z));

  const float* bp = partial + (size_t)pass * JC * N + i;
  float m0 = INF_F, m1 = INF_F, m2 = INF_F, m3 = INF_F;
  for (int c = 0; c < JC; c += 4) {
    m0 = fminf(m0, bp[(size_t)(c + 0) * N]);
    m1 = fminf(m1, bp[(size_t)(c + 1) * N]);
    m2 = fminf(m2, bp[(size_t)(c + 2) * N]);
    m3 = fminf(m3, bp[(size_t)(c + 3) * N]);
  }
  const float m = fminf(fminf(m0, m1), fminf(m2, m3));
  float d = sqrtf(fmaxf(sa + m, 0.0f));

  for (int off = 32; off > 0; off >>= 1) d += __shfl_down(d, off, 64);
  __shared__ float red[THREADS / 64];
  const int wave = threadIdx.x >> 6;
  const int lane = threadIdx.x & 63;
  if (lane == 0) red[wave] = d;
  __syncthreads();
  if (threadIdx.x == 0) {
    float s = 0.0f;
    for (int w = 0; w < THREADS / 64; ++w) s += red[w];
    atomicAdd(out, s);
  }
}

extern "C" void kernel_launch(void* const* d_in, const int* in_sizes, int n_in,
                              void* d_out, int out_size, void* d_ws, size_t ws_size,
                              hipStream_t stream) {
  const float* p1 = (const float*)d_in[0];
  const float* p2 = (const float*)d_in[1];
  float* out = (float*)d_out;
  float* partial = (float*)d_ws;

  // ws: partial[2][JC][N]. JC=64 -> 8 MB (proven available R4/R6/R7);
  // degrade if tight. jrange = N/JC <= 1024 fits the 16KB bls buffer.
  const size_t F = ws_size / sizeof(float);
  int JC = 64;
  while (JC > 16 && (size_t)(2 * JC) * N > F) JC >>= 1;
  const int jrange = N / JC;

  const int grid = 2 * IBLK * JC;            // 1024 @ JC=64
  chamfer_pass<<<dim3(grid), THREADS, 0, stream>>>(p1, p2, partial, out,
                                                   jrange, JC);
  chamfer_sum<<<dim3((2 * N) / THREADS), THREADS, 0, stream>>>(p1, p2, partial,
                                                               out, JC);
}